// Round 1
// baseline (4612.259 us; speedup 1.0000x reference)
//
#include <hip/hip_runtime.h>
#include <hip/hip_bf16.h>
#include <math.h>

#define V 32000
#define B 32
#define E 64
#define H 256
#define T 128
#define NROW (B*T)     // 4096 rows, row = t*B + b
#define VC 64          // vocab cols per block in logits kernel
#define NVB (V/VC)     // 500
#define RT 32          // rows per LDS tile in logits kernel

// ws layout (float offsets)
#define OFF_XS   0
#define OFF_XW   (OFF_XS + NROW*E)        //  262144
#define OFF_H    (OFF_XW + NROW*4*H)      // +4194304
#define OFF_PM   (OFF_H  + NROW*H)        // +1048576
#define OFF_PS   (OFF_PM + NVB*NROW)      // +2048000
#define OFF_TL   (OFF_PS + NVB*NROW)      // +2048000  (total ~38.4 MB)

// ---------------- kernel 1: embedding gather (teacher forcing) ----------------
__global__ void lstm_embed(const int* __restrict__ x, const float* __restrict__ emb,
                           const int* __restrict__ start, float* __restrict__ xs,
                           float* __restrict__ out) {
    int idx = blockIdx.x * 256 + threadIdx.x;
    if (idx == 0) out[0] = 0.f;               // zero accumulator each launch (graph-replay safe)
    if (idx >= T * B * E) return;
    int t   = idx / (B * E);
    int rem = idx - t * (B * E);
    int b   = rem >> 6;                        // /E
    int e   = rem & 63;                        // %E
    int tok = (t == 0) ? start[0] : x[b * T + (t - 1)];
    xs[idx] = emb[tok * E + e];
}

// ---------------- kernel 2: XW = xs @ [Wi|Wf|Wog|Wc] + bias -------------------
__global__ void lstm_xw(const float* __restrict__ xs, float* __restrict__ xw,
                        const float* __restrict__ Wi, const float* __restrict__ Wf,
                        const float* __restrict__ Wog, const float* __restrict__ Wc,
                        const float* __restrict__ bi, const float* __restrict__ bf,
                        const float* __restrict__ bog, const float* __restrict__ bc) {
    int idx = blockIdx.x * 256 + threadIdx.x;  // NROW*1024 outputs
    int row = idx >> 10;
    int gj  = idx & 1023;
    int g   = gj >> 8, j = gj & 255;
    const float* W    = (g == 0) ? Wi : (g == 1) ? Wf : (g == 2) ? Wog : Wc;
    const float* bias = (g == 0) ? bi : (g == 1) ? bf : (g == 2) ? bog : bc;
    float acc = bias[j];
    const float* xr = xs + row * E;
    #pragma unroll
    for (int e = 0; e < E; ++e) acc += xr[e] * W[e * H + j];
    xw[idx] = acc;
}

// ---------------- kernel 3: sequential recurrence, 1 block per batch row ------
__global__ __launch_bounds__(1024) void lstm_recur(
        const float* __restrict__ xw, float* __restrict__ h_all,
        const float* __restrict__ Ui, const float* __restrict__ Uf,
        const float* __restrict__ Uog, const float* __restrict__ Uc) {
    __shared__ float h_lds[H];
    __shared__ float c_lds[H];
    __shared__ float g_lds[4 * H];
    const int b   = blockIdx.x;
    const int tid = threadIdx.x;
    const int g   = tid >> 8, j = tid & 255;
    const float* U  = (g == 0) ? Ui : (g == 1) ? Uf : (g == 2) ? Uog : Uc;
    const float* Uj = U + j;
    if (tid < H) { h_lds[tid] = 0.f; c_lds[tid] = 0.f; }
    __syncthreads();
    for (int t = 0; t < T; ++t) {
        const int row = t * B + b;
        float acc = xw[row * (4 * H) + tid];
        #pragma unroll 8
        for (int k = 0; k < H; ++k) acc += h_lds[k] * Uj[k * H];
        g_lds[tid] = acc;
        __syncthreads();
        if (tid < H) {
            float iv = 1.f / (1.f + expf(-g_lds[tid]));
            float fv = 1.f / (1.f + expf(-g_lds[H + tid]));
            float ov = 1.f / (1.f + expf(-g_lds[2 * H + tid]));
            float cb = tanhf(g_lds[3 * H + tid]);
            float c  = fv * c_lds[tid] + iv * cb;
            c_lds[tid] = c;
            float h  = ov * tanhf(c);
            h_lds[tid] = h;
            h_all[row * H + tid] = h;
        }
        __syncthreads();
    }
}

// ------- kernel 4: fused logits GEMM + per-(row, vchunk) online logsumexp -----
__global__ __launch_bounds__(256) void lstm_logits(
        const float* __restrict__ h_all, const float* __restrict__ Wo,
        const float* __restrict__ bo, const int* __restrict__ x,
        float* __restrict__ pm, float* __restrict__ ps, float* __restrict__ tl) {
    __shared__ float h_tile[RT][H];        // 32 KB
    __shared__ float s_logit[RT][VC + 1];  // 8.3 KB (pad to kill bank conflicts)
    const int vbase = blockIdx.x * VC;
    const int tid   = threadIdx.x;
    const int col   = tid & (VC - 1);
    const int rsub  = tid >> 6;            // 0..3, each owns RT/4 = 8 rows
    const float bocol = bo[vbase + col];
    const float* wp = Wo + vbase + col;
    for (int rb = 0; rb < NROW / RT; ++rb) {
        for (int i = tid; i < RT * H; i += 256)
            h_tile[i >> 8][i & 255] = h_all[rb * RT * H + i];
        __syncthreads();
        float acc[RT / 4];
        #pragma unroll
        for (int r = 0; r < RT / 4; ++r) acc[r] = 0.f;
        #pragma unroll 4
        for (int k = 0; k < H; ++k) {
            float w = wp[(size_t)k * V];
            #pragma unroll
            for (int r = 0; r < RT / 4; ++r)
                acc[r] += h_tile[rsub * (RT / 4) + r][k] * w;
        }
        #pragma unroll
        for (int r = 0; r < RT / 4; ++r)
            s_logit[rsub * (RT / 4) + r][col] = acc[r] + bocol;
        __syncthreads();
        if (tid < RT) {
            const int r = tid;
            float m = -1e30f;
            for (int c = 0; c < VC; ++c) m = fmaxf(m, s_logit[r][c]);
            float s = 0.f;
            for (int c = 0; c < VC; ++c) s += expf(s_logit[r][c] - m);
            const int gr = rb * RT + r;
            const int tt = gr >> 5, bb = gr & 31;
            const int tgt = x[bb * T + tt];
            if (tgt >= vbase && tgt < vbase + VC)
                tl[gr] = s_logit[r][tgt - vbase];
            pm[blockIdx.x * NROW + gr] = m;
            ps[blockIdx.x * NROW + gr] = s;
        }
        __syncthreads();
    }
}

// ---------------- kernel 5: combine partials, reduce NLL ----------------------
__global__ __launch_bounds__(256) void lstm_lse(
        const float* __restrict__ pm, const float* __restrict__ ps,
        const float* __restrict__ tl, float* __restrict__ out) {
    const int row = blockIdx.x * 256 + threadIdx.x;
    float m = -1e30f, s = 0.f;
    for (int c = 0; c < NVB; ++c) {
        float mc = pm[c * NROW + row];
        float sc = ps[c * NROW + row];
        if (mc > m) { s = s * expf(m - mc) + sc; m = mc; }
        else        { s += sc * expf(mc - m); }
    }
    float nll = (m + logf(s)) - tl[row];
    __shared__ float red[256];
    red[threadIdx.x] = nll;
    __syncthreads();
    for (int off = 128; off > 0; off >>= 1) {
        if (threadIdx.x < off) red[threadIdx.x] += red[threadIdx.x + off];
        __syncthreads();
    }
    if (threadIdx.x == 0) atomicAdd(out, red[0]);
}

extern "C" void kernel_launch(void* const* d_in, const int* in_sizes, int n_in,
                              void* d_out, int out_size, void* d_ws, size_t ws_size,
                              hipStream_t stream) {
    const int*   x     = (const int*)d_in[0];
    const float* emb   = (const float*)d_in[1];
    const float* Wi    = (const float*)d_in[2];
    const float* Ui    = (const float*)d_in[3];
    const float* bi    = (const float*)d_in[4];
    const float* Wf    = (const float*)d_in[5];
    const float* Uf    = (const float*)d_in[6];
    const float* bf    = (const float*)d_in[7];
    const float* Wog   = (const float*)d_in[8];
    const float* Uog   = (const float*)d_in[9];
    const float* bog   = (const float*)d_in[10];
    const float* Wc    = (const float*)d_in[11];
    const float* Uc    = (const float*)d_in[12];
    const float* bc    = (const float*)d_in[13];
    const float* Wo    = (const float*)d_in[14];
    const float* bo    = (const float*)d_in[15];
    const int*   start = (const int*)d_in[16];
    float* ws  = (float*)d_ws;
    float* out = (float*)d_out;

    lstm_embed <<<(T * B * E + 255) / 256, 256, 0, stream>>>(x, emb, start, ws + OFF_XS, out);
    lstm_xw    <<<(NROW * 4 * H) / 256,    256, 0, stream>>>(ws + OFF_XS, ws + OFF_XW,
                                                             Wi, Wf, Wog, Wc, bi, bf, bog, bc);
    lstm_recur <<<B, 1024, 0, stream>>>(ws + OFF_XW, ws + OFF_H, Ui, Uf, Uog, Uc);
    lstm_logits<<<NVB, 256, 0, stream>>>(ws + OFF_H, Wo, bo, x,
                                         ws + OFF_PM, ws + OFF_PS, ws + OFF_TL);
    lstm_lse   <<<NROW / 256, 256, 0, stream>>>(ws + OFF_PM, ws + OFF_PS, ws + OFF_TL, out);
}

// Round 2
// 1400.559 us; speedup vs baseline: 3.2932x; 3.2932x over previous
//
#include <hip/hip_runtime.h>
#include <hip/hip_bf16.h>
#include <math.h>

#define V 32000
#define B 32
#define E 64
#define H 256
#define T 128
#define NROW (B*T)     // 4096 rows, row = t*B + b
#define NC 128         // vocab cols per block (logits)
#define NVB (V/NC)     // 250
#define MR 128         // rows per block (logits)

typedef __attribute__((ext_vector_type(8))) short bf16x8;
typedef __attribute__((ext_vector_type(4))) float f32x4;
typedef __attribute__((ext_vector_type(8))) unsigned short u16x8;

// ws layout (float offsets)
#define OFF_XS   0
#define OFF_XW   (OFF_XS + NROW*E)          // 262144   (16 MB region; reused for WoT after recur)
#define OFF_HB   (OFF_XW + NROW*4*H)        // 4456448  (h bf16: NROW*H ushort = 2 MB)
#define OFF_PM   (OFF_HB + NROW*H/2)        // 4980736
#define OFF_PS   (OFF_PM + NVB*NROW)        // 6004736
#define OFF_TL   (OFF_PS + NVB*NROW)        // 7028736  (+4096) total ~28.1 MB

static __device__ __forceinline__ unsigned short f2bf(float f) {
    union { float f; unsigned int u; } x; x.f = f;
    unsigned int r = x.u + 0x7fffu + ((x.u >> 16) & 1u);   // RNE
    return (unsigned short)(r >> 16);
}

// ---------------- kernel 1: embedding gather (teacher forcing) ----------------
__global__ void lstm_embed(const int* __restrict__ x, const float* __restrict__ emb,
                           const int* __restrict__ start, float* __restrict__ xs,
                           float* __restrict__ out) {
    int idx = blockIdx.x * 256 + threadIdx.x;
    if (idx == 0) out[0] = 0.f;               // zero accumulator each launch (graph-replay safe)
    if (idx >= T * B * E) return;
    int t   = idx / (B * E);
    int rem = idx - t * (B * E);
    int b   = rem >> 6;
    int e   = rem & 63;
    int tok = (t == 0) ? start[0] : x[b * T + (t - 1)];
    xs[idx] = emb[tok * E + e];
}

// ---------------- kernel 2: XW = xs @ [Wi|Wf|Wog|Wc] + bias -------------------
__global__ void lstm_xw(const float* __restrict__ xs, float* __restrict__ xw,
                        const float* __restrict__ Wi, const float* __restrict__ Wf,
                        const float* __restrict__ Wog, const float* __restrict__ Wc,
                        const float* __restrict__ bi, const float* __restrict__ bf,
                        const float* __restrict__ bog, const float* __restrict__ bc) {
    int idx = blockIdx.x * 256 + threadIdx.x;
    int row = idx >> 10;
    int gj  = idx & 1023;
    int g   = gj >> 8, j = gj & 255;
    const float* W    = (g == 0) ? Wi : (g == 1) ? Wf : (g == 2) ? Wog : Wc;
    const float* bias = (g == 0) ? bi : (g == 1) ? bf : (g == 2) ? bog : bc;
    float acc = bias[j];
    const float* xr = xs + row * E;
    #pragma unroll
    for (int e = 0; e < E; ++e) acc += xr[e] * W[e * H + j];
    xw[idx] = acc;
}

// ---------------- kernel 3: sequential recurrence, 1 block per batch row ------
__global__ __launch_bounds__(1024) void lstm_recur(
        const float* __restrict__ xw, unsigned short* __restrict__ hb,
        const float* __restrict__ Ui, const float* __restrict__ Uf,
        const float* __restrict__ Uog, const float* __restrict__ Uc) {
    __shared__ float h_lds[H];
    __shared__ float c_lds[H];
    __shared__ float g_lds[4 * H];
    const int b   = blockIdx.x;
    const int tid = threadIdx.x;
    const int g   = tid >> 8, j = tid & 255;
    const float* U  = (g == 0) ? Ui : (g == 1) ? Uf : (g == 2) ? Uog : Uc;
    const float* Uj = U + j;
    if (tid < H) { h_lds[tid] = 0.f; c_lds[tid] = 0.f; }
    __syncthreads();
    for (int t = 0; t < T; ++t) {
        const int row = t * B + b;
        float acc = xw[row * (4 * H) + tid];
        #pragma unroll 8
        for (int k = 0; k < H; ++k) acc += h_lds[k] * Uj[k * H];
        g_lds[tid] = acc;
        __syncthreads();
        if (tid < H) {
            float iv = 1.f / (1.f + expf(-g_lds[tid]));
            float fv = 1.f / (1.f + expf(-g_lds[H + tid]));
            float ov = 1.f / (1.f + expf(-g_lds[2 * H + tid]));
            float cb = tanhf(g_lds[3 * H + tid]);
            float c  = fv * c_lds[tid] + iv * cb;
            c_lds[tid] = c;
            float h  = ov * tanhf(c);
            h_lds[tid] = h;
            hb[row * H + tid] = f2bf(h);
        }
        __syncthreads();
    }
}

// -------- kernel 4: Wo [K=256][V] fp32  ->  WoT [V][K=256] bf16 (transpose) ---
__global__ __launch_bounds__(256) void lstm_wot(const float* __restrict__ Wo,
                                                unsigned short* __restrict__ WoT) {
    __shared__ unsigned short tle[64][65];
    const int n0 = blockIdx.x * 64, k0 = blockIdx.y * 64;
    const int tid = threadIdx.x;
    for (int i = tid; i < 64 * 64; i += 256) {
        int kk = i >> 6, nn = i & 63;
        tle[kk][nn] = f2bf(Wo[(size_t)(k0 + kk) * V + n0 + nn]);
    }
    __syncthreads();
    for (int c = tid; c < 512; c += 256) {
        int nn = c >> 3, kc = c & 7;
        u16x8 v;
        #pragma unroll
        for (int e = 0; e < 8; ++e) v[e] = tle[kc * 8 + e][nn];
        *(u16x8*)(WoT + (size_t)(n0 + nn) * H + k0 + kc * 8) = v;
    }
}

// ------ kernel 5: bf16 MFMA logits GEMM + fused per-(row,vchunk) partials -----
__global__ __launch_bounds__(512) void lstm_logits_mfma(
        const unsigned short* __restrict__ hb, const unsigned short* __restrict__ WoT,
        const float* __restrict__ bo, const int* __restrict__ x,
        float* __restrict__ pm, float* __restrict__ ps, float* __restrict__ tl) {
    __shared__ union {
        unsigned short ab[2][MR * H];   // [0]=A tile 64KB, [1]=B tile 64KB
        float lg[MR * 132];             // logits buffer (67.6KB), used after MFMA
    } sm;
    const int tid = threadIdx.x;
    const int vb  = blockIdx.x * NC;
    const int r0  = blockIdx.y * MR;

    // ---- stage A (h rows) and B (WoT rows), reg -> XOR-swizzled LDS ----
    const uint4* srcA = (const uint4*)(hb  + (size_t)r0 * H);
    const uint4* srcB = (const uint4*)(WoT + (size_t)vb * H);
    for (int c = tid; c < MR * H / 8; c += 512) {     // 4096 16B-chunks each
        int row = c >> 5, c16 = c & 31;
        uint4 va = srcA[c];
        *(uint4*)((char*)sm.ab[0] + row * 512 + ((c16 ^ (row & 7)) << 4)) = va;
        uint4 vbv = srcB[c];
        *(uint4*)((char*)sm.ab[1] + row * 512 + ((c16 ^ (row & 7)) << 4)) = vbv;
    }
    __syncthreads();

    const int lane = tid & 63, wid = tid >> 6;
    const int wr = wid >> 2, wc = wid & 3;            // 2x4 wave grid
    const int lr = lane & 15, lg = lane >> 4;
    const int swz = lr & 7;
    f32x4 acc[4][2] = {};
    const char* aBase = (const char*)sm.ab[0] + (wr * 64 + lr) * 512;
    const char* bBase = (const char*)sm.ab[1] + (wc * 32 + lr) * 512;
    #pragma unroll
    for (int ks = 0; ks < 8; ++ks) {
        bf16x8 a[4], bfr[2];
        #pragma unroll
        for (int mf = 0; mf < 4; ++mf)
            a[mf] = *(const bf16x8*)(aBase + mf * 16 * 512 + (((ks * 4 + lg) ^ swz) << 4));
        #pragma unroll
        for (int nf = 0; nf < 2; ++nf)
            bfr[nf] = *(const bf16x8*)(bBase + nf * 16 * 512 + (((ks * 4 + lg) ^ swz) << 4));
        #pragma unroll
        for (int mf = 0; mf < 4; ++mf)
            #pragma unroll
            for (int nf = 0; nf < 2; ++nf)
                acc[mf][nf] = __builtin_amdgcn_mfma_f32_16x16x32_bf16(a[mf], bfr[nf], acc[mf][nf], 0, 0, 0);
    }
    __syncthreads();

    // ---- write logits (+bias) to LDS ----
    float bocol[2];
    #pragma unroll
    for (int nf = 0; nf < 2; ++nf) bocol[nf] = bo[vb + wc * 32 + nf * 16 + lr];
    #pragma unroll
    for (int mf = 0; mf < 4; ++mf)
        #pragma unroll
        for (int nf = 0; nf < 2; ++nf)
            #pragma unroll
            for (int r = 0; r < 4; ++r) {
                int row = wr * 64 + mf * 16 + lg * 4 + r;   // D: row=(lane>>4)*4+reg
                int col = wc * 32 + nf * 16 + lr;           //    col=lane&15
                sm.lg[row * 132 + col] = acc[mf][nf][r] + bocol[nf];
            }
    __syncthreads();

    // ---- per-row max & sumexp over this block's NC cols (4 threads/row) ----
    {
        const int row = tid >> 2, q = tid & 3;
        const float* lp = &sm.lg[row * 132 + q * 32];
        float m = -1e30f;
        #pragma unroll
        for (int i = 0; i < 32; ++i) m = fmaxf(m, lp[i]);
        m = fmaxf(m, __shfl_xor(m, 1));
        m = fmaxf(m, __shfl_xor(m, 2));
        float s = 0.f;
        #pragma unroll
        for (int i = 0; i < 32; ++i) s += expf(lp[i] - m);
        s += __shfl_xor(s, 1);
        s += __shfl_xor(s, 2);
        if (q == 0) {
            const int gr = r0 + row;
            pm[(size_t)blockIdx.x * NROW + gr] = m;
            ps[(size_t)blockIdx.x * NROW + gr] = s;
            const int tt = gr >> 5, bb = gr & 31;
            const int tgt = x[bb * T + tt];
            if (tgt >= vb && tgt < vb + NC)
                tl[gr] = sm.lg[row * 132 + (tgt - vb)];
        }
    }
}

// ---------------- kernel 6: combine partials, reduce NLL ----------------------
__global__ __launch_bounds__(256) void lstm_lse(
        const float* __restrict__ pm, const float* __restrict__ ps,
        const float* __restrict__ tl, float* __restrict__ out) {
    const int row = blockIdx.x * 256 + threadIdx.x;
    float m = -1e30f, s = 0.f;
    for (int c = 0; c < NVB; ++c) {
        float mc = pm[(size_t)c * NROW + row];
        float sc = ps[(size_t)c * NROW + row];
        if (mc > m) { s = s * expf(m - mc) + sc; m = mc; }
        else        { s += sc * expf(mc - m); }
    }
    float nll = (m + logf(s)) - tl[row];
    __shared__ float red[256];
    red[threadIdx.x] = nll;
    __syncthreads();
    for (int off = 128; off > 0; off >>= 1) {
        if (threadIdx.x < off) red[threadIdx.x] += red[threadIdx.x + off];
        __syncthreads();
    }
    if (threadIdx.x == 0) atomicAdd(out, red[0]);
}

extern "C" void kernel_launch(void* const* d_in, const int* in_sizes, int n_in,
                              void* d_out, int out_size, void* d_ws, size_t ws_size,
                              hipStream_t stream) {
    const int*   x     = (const int*)d_in[0];
    const float* emb   = (const float*)d_in[1];
    const float* Wi    = (const float*)d_in[2];
    const float* Ui    = (const float*)d_in[3];
    const float* bi    = (const float*)d_in[4];
    const float* Wf    = (const float*)d_in[5];
    const float* Uf    = (const float*)d_in[6];
    const float* bf    = (const float*)d_in[7];
    const float* Wog   = (const float*)d_in[8];
    const float* Uog   = (const float*)d_in[9];
    const float* bog   = (const float*)d_in[10];
    const float* Wc    = (const float*)d_in[11];
    const float* Uc    = (const float*)d_in[12];
    const float* bc    = (const float*)d_in[13];
    const float* Wo    = (const float*)d_in[14];
    const float* bo    = (const float*)d_in[15];
    const int*   start = (const int*)d_in[16];
    float* ws  = (float*)d_ws;
    float* out = (float*)d_out;

    float*          xs  = ws + OFF_XS;
    float*          xw  = ws + OFF_XW;
    unsigned short* WoT = (unsigned short*)(ws + OFF_XW);   // aliases xw (dead after recur)
    unsigned short* hbf = (unsigned short*)(ws + OFF_HB);
    float*          pm  = ws + OFF_PM;
    float*          psB = ws + OFF_PS;
    float*          tlB = ws + OFF_TL;

    lstm_embed <<<(T * B * E + 255) / 256, 256, 0, stream>>>(x, emb, start, xs, out);
    lstm_xw    <<<(NROW * 4 * H) / 256,    256, 0, stream>>>(xs, xw, Wi, Wf, Wog, Wc, bi, bf, bog, bc);
    lstm_recur <<<B, 1024, 0, stream>>>(xw, hbf, Ui, Uf, Uog, Uc);
    lstm_wot   <<<dim3(V / 64, H / 64), 256, 0, stream>>>(Wo, WoT);
    lstm_logits_mfma<<<dim3(NVB, NROW / MR), 512, 0, stream>>>(hbf, WoT, bo, x, pm, psB, tlB);
    lstm_lse   <<<NROW / 256, 256, 0, stream>>>(pm, psB, tlB, out);
}